// Round 7
// baseline (362.872 us; speedup 1.0000x reference)
//
#include <hip/hip_runtime.h>

// LengthRegulator: expand x (B,T,H) by per-token durations into (B,MAXLEN,H),
// plus sinusoidal positional rows per within-token offset, plus mel lengths.
// B=64, T=160, H=256, MAXLEN=2000 (fixed by the harness's setup_inputs).
//
// v5: DIAGNOSTIC round. v0/v3/v4 (radically different structures) all land at
// 267-280 us total; the ~105 us beyond the poison fill is invariant. Either
// (a) expand really streams at only ~2.6 TB/s, or (b) expand is ~45 us
// (roofline) and ~60 us is fixed harness reset/dispatch overhead. The top-5
// counter table can't show our <159 us kernel, so: run the expand work
// nrep=4 times (idempotent identical re-stores; final memory unchanged).
// At 4x duration the expand kernel MUST enter the top-5 table and reveal its
// true dur/WRITE_SIZE/hbm_gbps. nrep is a runtime arg + per-pass memory
// clobber so the compiler cannot fold or dead-store-eliminate the passes.
constexpr int B      = 64;
constexpr int T      = 160;
constexpr int H      = 256;
constexpr int MAXLEN = 2000;
constexpr int FPB    = 16;   // frames per tile (4 waves x 4 contiguous frames)
constexpr int NTH    = 256;
constexpr int TPB_X  = 32;   // persistent x-blocks per batch (32*64 = 2048 blocks)

// ---------------- Kernel A: per-batch scan + map build (64 blocks) ----------
// map[b*MAXLEN + f] = (token << 8) | pos_within   for valid frames (pw in 0..11)
//                   = -1                          for the invalid tail
__global__ __launch_bounds__(NTH) void build_map_kernel(
    const int* __restrict__ duration,
    int*       __restrict__ map,
    float*     __restrict__ out)      // only for the mel_len chunk
{
    __shared__ int s_scan[NTH];
    const int b   = blockIdx.x;
    const int tid = threadIdx.x;

    int d = (tid < T) ? duration[b * T + tid] : 0;
    s_scan[tid] = d;
    __syncthreads();
    #pragma unroll
    for (int off = 1; off < NTH; off <<= 1) {
        int v   = s_scan[tid];
        int add = (tid >= off) ? s_scan[tid - off] : 0;
        __syncthreads();
        s_scan[tid] = v + add;
        __syncthreads();
    }
    const int csum    = s_scan[tid];        // inclusive prefix (valid for tid < T)
    const int excl    = csum - d;           // exclusive prefix
    const int mel_len = s_scan[T - 1];

    if (tid == 0)
        out[(size_t)2 * B * MAXLEN * H + b] = (float)mel_len;

    int* bm = map + b * MAXLEN;

    // invalid tail
    for (int f = mel_len + tid; f < MAXLEN; f += NTH)
        bm[f] = -1;

    // scatter: token tid owns frames [excl, csum). duration < 12 so pw fits 8 bits.
    if (tid < T) {
        for (int f = excl; f < csum; ++f)
            bm[f] = (tid << 8) | (f - excl);
    }
}

// ---------------- Kernel B: persistent streaming expand (32 x 64 blocks) ----
// nrep: diagnostic repeat count (idempotent; final memory identical for any
// nrep >= 1). Memory clobber per pass blocks cross-pass store elimination.
__global__ __launch_bounds__(NTH) void expand_kernel(
    const float* __restrict__ x,
    const float* __restrict__ pos_enc,
    const int*   __restrict__ map,
    float*       __restrict__ out,
    int nrep)
{
    const int tid  = threadIdx.x;
    const int b    = blockIdx.y;
    const int wave = tid >> 6;   // 0..3
    const int lane = tid & 63;   // float4 index within the 256-wide row

    const float* xb   = x   + (size_t)b * T * H;
    float*       outb = out + (size_t)b * MAXLEN * H;
    float*       posb = outb + (size_t)B * MAXLEN * H;
    const int*   bm   = map + b * MAXLEN;

    constexpr int NTILE = MAXLEN / FPB;   // 125 tiles per batch
    for (int r = 0; r < nrep; ++r) {
        for (int tx = blockIdx.x; tx < NTILE; tx += TPB_X) {
            const int fw = tx * FPB + 4 * wave;        // 4 contiguous frames/wave
            const int4 m4 = *(const int4*)(bm + fw);   // wave-uniform 16B broadcast
            const int mm[4] = { m4.x, m4.y, m4.z, m4.w };

            float4 xo[4], po[4];
            #pragma unroll
            for (int j = 0; j < 4; ++j) {
                const int msel = (mm[j] < 0) ? 0 : mm[j];
                const int t  = msel >> 8;
                const int pw = msel & 255;
                xo[j] = ((const float4*)(xb      + (size_t)t  * H))[lane];
                po[j] = ((const float4*)(pos_enc + (size_t)pw * H))[lane];
            }
            #pragma unroll
            for (int j = 0; j < 4; ++j) {
                const float s = (mm[j] >= 0) ? 1.0f : 0.0f;
                const int   f = fw + j;
                float4 a = make_float4(xo[j].x * s, xo[j].y * s, xo[j].z * s, xo[j].w * s);
                float4 p = make_float4(po[j].x * s, po[j].y * s, po[j].z * s, po[j].w * s);
                ((float4*)(outb + (size_t)f * H))[lane] = a;
                ((float4*)(posb + (size_t)f * H))[lane] = p;
            }
        }
        // keep each pass's stores observable (no cross-pass DSE / hoisting)
        asm volatile("" ::: "memory");
    }
}

// ---------------- Fallback: original fused kernel (if ws too small) ---------
__global__ __launch_bounds__(NTH) void lr_kernel(
    const float* __restrict__ x,
    const float* __restrict__ pos_enc,
    const int*   __restrict__ duration,
    float*       __restrict__ out)
{
    __shared__ int s_scan[NTH];
    __shared__ int s_csum[T];
    __shared__ int s_excl[T];

    const int b   = blockIdx.y;
    const int tid = threadIdx.x;

    int d = (tid < T) ? duration[b * T + tid] : 0;
    s_scan[tid] = d;
    __syncthreads();
    #pragma unroll
    for (int off = 1; off < NTH; off <<= 1) {
        int v   = s_scan[tid];
        int add = (tid >= off) ? s_scan[tid - off] : 0;
        __syncthreads();
        s_scan[tid] = v + add;
        __syncthreads();
    }
    if (tid < T) {
        s_csum[tid] = s_scan[tid];
        s_excl[tid] = s_scan[tid] - d;
    }
    __syncthreads();

    const int mel_len = s_csum[T - 1];
    if (blockIdx.x == 0 && tid == 0) {
        out[(size_t)2 * B * MAXLEN * H + b] = (float)mel_len;
    }

    const int wave = tid >> 6;
    const int lane = tid & 63;
    const size_t out_base = (size_t)b * MAXLEN * H;
    const size_t pos_base = (size_t)B * MAXLEN * H + out_base;
    const int f0 = blockIdx.x * FPB;

    for (int i = wave; i < FPB; i += 4) {
        const int f = f0 + i;
        if (f >= MAXLEN) break;
        const bool valid = (f < mel_len);

        int lo = 0, hi = T;
        while (lo < hi) {
            int mid = (lo + hi) >> 1;
            if (s_csum[mid] <= f) lo = mid + 1; else hi = mid;
        }
        const int idx = min(lo, T - 1);

        float4 xo = make_float4(0.f, 0.f, 0.f, 0.f);
        float4 po = xo;
        if (valid) {
            const int pw = f - s_excl[idx];
            xo = ((const float4*)(x + ((size_t)b * T + idx) * H))[lane];
            po = ((const float4*)(pos_enc + (size_t)pw * H))[lane];
        }
        ((float4*)(out + out_base + (size_t)f * H))[lane] = xo;
        ((float4*)(out + pos_base + (size_t)f * H))[lane] = po;
    }
}

extern "C" void kernel_launch(void* const* d_in, const int* in_sizes, int n_in,
                              void* d_out, int out_size, void* d_ws, size_t ws_size,
                              hipStream_t stream)
{
    const float* x        = (const float*)d_in[0];
    const float* pos_enc  = (const float*)d_in[1];
    const int*   duration = (const int*)d_in[2];
    float*       out      = (float*)d_out;

    const size_t map_bytes = (size_t)B * MAXLEN * sizeof(int);
    if (d_ws != nullptr && ws_size >= map_bytes) {
        int* map = (int*)d_ws;
        build_map_kernel<<<dim3(B), NTH, 0, stream>>>(duration, map, out);
        // nrep=4: diagnostic amplification so expand enters the top-5 counter
        // table. Idempotent — correctness unaffected.
        expand_kernel<<<dim3(TPB_X, B), NTH, 0, stream>>>(x, pos_enc, map, out, 4);
    } else {
        dim3 grid((MAXLEN + FPB - 1) / FPB, B);
        lr_kernel<<<grid, NTH, 0, stream>>>(x, pos_enc, duration, out);
    }
}

// Round 8
// 274.076 us; speedup vs baseline: 1.3240x; 1.3240x over previous
//
#include <hip/hip_runtime.h>

// LengthRegulator: expand x (B,T,H) by per-token durations into (B,MAXLEN,H),
// plus sinusoidal positional rows per within-token offset, plus mel lengths.
// B=64, T=160, H=256, MAXLEN=2000 (fixed by the harness's setup_inputs).
//
// v6 (final): single fused persistent-grid kernel.
// Diagnostic (R7, nrep=4 amplification) established: one expand pass costs
// ~30-45 us ~= the 262 MB write roofline (42 us @ 6.3 TB/s); the remaining
// ~60 us of the invariant 267-272 us total is fixed harness reset/dispatch
// overhead, and ~160 us is the harness poison fill. All kernel structures
// (fused+search / split+map / persistent) measured identical -> scan and
// search are free; only stores matter. This version: ONE launch (saves the
// second dispatch), 2048 persistent blocks (8/CU), per-block scan of the
// 160 durations, branchless gather/store body, plain cached float4 stores.
constexpr int B      = 64;
constexpr int T      = 160;
constexpr int H      = 256;
constexpr int MAXLEN = 2000;
constexpr int FPB    = 16;   // frames per tile (4 waves x 4 contiguous frames)
constexpr int NTH    = 256;
constexpr int TPB_X  = 32;   // persistent x-blocks per batch (32*64 = 2048 blocks)

__global__ __launch_bounds__(NTH) void lr_fused_kernel(
    const float* __restrict__ x,
    const float* __restrict__ pos_enc,
    const int*   __restrict__ duration,
    float*       __restrict__ out)
{
    __shared__ int s_scan[NTH];
    __shared__ int s_csum[T];
    __shared__ int s_excl[T];

    const int b   = blockIdx.y;
    const int tid = threadIdx.x;

    // --- inclusive scan of duration[b, :] (160 elems, padded to 256) ---
    int d = (tid < T) ? duration[b * T + tid] : 0;
    s_scan[tid] = d;
    __syncthreads();
    #pragma unroll
    for (int off = 1; off < NTH; off <<= 1) {
        int v   = s_scan[tid];
        int add = (tid >= off) ? s_scan[tid - off] : 0;
        __syncthreads();
        s_scan[tid] = v + add;
        __syncthreads();
    }
    if (tid < T) {
        s_csum[tid] = s_scan[tid];
        s_excl[tid] = s_scan[tid] - d;   // exclusive prefix
    }
    __syncthreads();

    const int mel_len = s_csum[T - 1];
    if (blockIdx.x == 0 && tid == 0)
        out[(size_t)2 * B * MAXLEN * H + b] = (float)mel_len;

    const int wave = tid >> 6;   // 0..3
    const int lane = tid & 63;   // float4 index within the 256-wide row

    const float* xb   = x   + (size_t)b * T * H;
    float*       outb = out + (size_t)b * MAXLEN * H;
    float*       posb = outb + (size_t)B * MAXLEN * H;

    constexpr int NTILE = MAXLEN / FPB;   // 125 tiles per batch
    for (int tx = blockIdx.x; tx < NTILE; tx += TPB_X) {
        const int fw = tx * FPB + 4 * wave;      // 4 contiguous frames/wave

        // per-frame token lookup: wave-uniform LDS binary search (measured
        // free vs the store stream), then branchless gather.
        int   tk[4], pw[4];
        float sc[4];
        #pragma unroll
        for (int j = 0; j < 4; ++j) {
            const int f = fw + j;
            int lo = 0, hi = T;
            while (lo < hi) {
                int mid = (lo + hi) >> 1;
                if (s_csum[mid] <= f) lo = mid + 1; else hi = mid;
            }
            const int idx = min(lo, T - 1);
            const bool valid = (f < mel_len);
            tk[j] = valid ? idx : 0;
            pw[j] = valid ? (f - s_excl[idx]) : 0;   // 0..11
            sc[j] = valid ? 1.0f : 0.0f;
        }

        // all 8 row loads in flight before any store (invalid frames read
        // token 0 / pos 0 - broadcast L2 hits - and are zeroed by sc[j])
        float4 xo[4], po[4];
        #pragma unroll
        for (int j = 0; j < 4; ++j) {
            xo[j] = ((const float4*)(xb      + (size_t)tk[j] * H))[lane];
            po[j] = ((const float4*)(pos_enc + (size_t)pw[j] * H))[lane];
        }
        #pragma unroll
        for (int j = 0; j < 4; ++j) {
            const int f = fw + j;
            float4 a = make_float4(xo[j].x * sc[j], xo[j].y * sc[j],
                                   xo[j].z * sc[j], xo[j].w * sc[j]);
            float4 p = make_float4(po[j].x * sc[j], po[j].y * sc[j],
                                   po[j].z * sc[j], po[j].w * sc[j]);
            ((float4*)(outb + (size_t)f * H))[lane] = a;
            ((float4*)(posb + (size_t)f * H))[lane] = p;
        }
    }
}

extern "C" void kernel_launch(void* const* d_in, const int* in_sizes, int n_in,
                              void* d_out, int out_size, void* d_ws, size_t ws_size,
                              hipStream_t stream)
{
    const float* x        = (const float*)d_in[0];
    const float* pos_enc  = (const float*)d_in[1];
    const int*   duration = (const int*)d_in[2];
    float*       out      = (float*)d_out;

    lr_fused_kernel<<<dim3(TPB_X, B), NTH, 0, stream>>>(x, pos_enc, duration, out);
}